// Round 1
// baseline (6088.926 us; speedup 1.0000x reference)
//
#include <hip/hip_runtime.h>
#include <math.h>

// Problem constants (from reference)
#define N_ROWS   16384
#define NC       1000
#define KVAL     5.0f
#define ALPHA    0.025f
#define N_ITER   80
#define N_BISECT 50
#define EPS_P    1e-6f
#define EPJ      16      // elements per lane: 16*64 = 1024 >= 1000

// One wave (64 lanes) per row. Lane holds elements e = j*64 + lane, j in [0,16).
// Row-level scalars (norm, min/max, bisection sum) via 64-wide shuffle butterflies.

__global__ __launch_bounds__(256, 4) void pgd_kernel(
        const float* __restrict__ x,
        const int*   __restrict__ y,
        double*      __restrict__ acc) {
    const int wave = threadIdx.x >> 6;     // 0..3 (4 rows per block)
    const int lane = threadIdx.x & 63;
    const int row  = (blockIdx.x << 2) + wave;

    const float* __restrict__ xr = x + (size_t)row * NC;

    float c[EPJ];   // normalized logits (tau = 1)
    float p[EPJ];
    float v[EPJ];

    // ---- load row + sum of squares (for L2 normalize) ----
    float ss = 0.f;
#pragma unroll
    for (int j = 0; j < EPJ; ++j) {
        const int e = j * 64 + lane;
        float xv = (e < NC) ? xr[e] : 0.f;
        c[j] = xv;
        ss += xv * xv;
    }
#pragma unroll
    for (int m = 1; m < 64; m <<= 1) ss += __shfl_xor(ss, m, 64);

    float norm = fmaxf(sqrtf(ss), 1e-12f);
#pragma unroll
    for (int j = 0; j < EPJ; ++j) c[j] = c[j] / norm;

#pragma unroll
    for (int j = 0; j < EPJ; ++j) p[j] = KVAL / (float)NC;  // 0.005

    // ---- 80 PGD iterations, each with the reference's 50-step bisection ----
    for (int it = 0; it < N_ITER; ++it) {
        // gradient ascent step: v = p + alpha * (c + log1p(-pc) - log(pc))
        float vmin =  1e30f;
        float vmax = -1e30f;
#pragma unroll
        for (int j = 0; j < EPJ; ++j) {
            float pc = fminf(fmaxf(p[j], EPS_P), 1.f - EPS_P);
            float g  = c[j] + log1pf(-pc) - logf(pc);
            float vj = p[j] + ALPHA * g;
            const bool valid = (j * 64 + lane) < NC;   // only j==15 can be invalid
            vj = valid ? vj : -1e30f;                  // pads contribute 0 to clip-sum
            v[j] = vj;
            vmin = fminf(vmin, valid ? vj : 1e30f);
            vmax = fmaxf(vmax, vj);
        }
#pragma unroll
        for (int m = 1; m < 64; m <<= 1) {
            vmin = fminf(vmin, __shfl_xor(vmin, m, 64));
            vmax = fmaxf(vmax, __shfl_xor(vmax, m, 64));
        }

        // capped-simplex projection via bisection (faithful to reference)
        float lo = vmin - 1.f;
        float hi = vmax;
        for (int b = 0; b < N_BISECT; ++b) {
            const float mid = 0.5f * (lo + hi);
            float s = 0.f;
#pragma unroll
            for (int j = 0; j < EPJ; ++j)
                s += fminf(fmaxf(v[j] - mid, 0.f), 1.f);
#pragma unroll
            for (int m = 1; m < 64; m <<= 1) s += __shfl_xor(s, m, 64);
            const bool big = (s > KVAL);
            lo = big ? mid : lo;
            hi = big ? hi  : mid;
        }
        const float nu = 0.5f * (lo + hi);
#pragma unroll
        for (int j = 0; j < EPJ; ++j)
            p[j] = fminf(fmaxf(v[j] - nu, 0.f), 1.f);
    }

    // ---- pick p[y], loss = -log(p_y + 1e-8) ----
    const int yv = y[row];          // wave-uniform
    const int jy = yv >> 6;
    const int ly = yv & 63;
    float sel = 0.f;
#pragma unroll
    for (int j = 0; j < EPJ; ++j) sel = (j == jy) ? p[j] : sel;
    const float py   = __shfl(sel, ly, 64);
    const float loss = -logf(py + 1e-8f);

    __shared__ float partial[4];
    if (lane == 0) partial[wave] = loss;
    __syncthreads();
    if (threadIdx.x == 0) {
        double t = (double)partial[0] + (double)partial[1]
                 + (double)partial[2] + (double)partial[3];
        atomicAdd(acc, t);
    }
}

__global__ void finalize_kernel(const double* __restrict__ acc,
                                float* __restrict__ out) {
    out[0] = (float)(acc[0] / (double)N_ROWS);
}

extern "C" void kernel_launch(void* const* d_in, const int* in_sizes, int n_in,
                              void* d_out, int out_size, void* d_ws, size_t ws_size,
                              hipStream_t stream) {
    const float* x = (const float*)d_in[0];
    const int*   y = (const int*)d_in[1];
    double* acc = (double*)d_ws;

    hipMemsetAsync(acc, 0, sizeof(double), stream);   // ws is poisoned 0xAA each call
    pgd_kernel<<<N_ROWS / 4, 256, 0, stream>>>(x, y, acc);
    finalize_kernel<<<1, 1, 0, stream>>>(acc, (float*)d_out);
}

// Round 4
// 758.272 us; speedup vs baseline: 8.0300x; 8.0300x over previous
//
#include <hip/hip_runtime.h>
#include <math.h>

// Problem constants (from reference)
#define N_ROWS    16384
#define NC        1000
#define KVAL      5.0f
#define ALPHA     0.025f
#define N_ITER    80
#define MAX_SOLVE 16        // exact-Newton passes (monotone on convex s; early exit ~3-8)
#define EPS_P     1e-6f
#define EPJ       16        // elements per lane: 16*64 = 1024 >= 1000
#define LN2       0.69314718055994531f

// One wave (64 lanes) per row. Lane holds elements e = j*64 + lane.
// Row scalars via DPP row_shr/row_bcast reduction (VALU pipe, no LDS).

template <int CTRL>
__device__ __forceinline__ float dpp_add(float x) {
    int t = __builtin_amdgcn_update_dpp(0, __float_as_int(x), CTRL, 0xf, 0xf, true);
    return x + __int_as_float(t);
}

// Full 64-lane sum -> broadcast via readlane(63) (uniform).
__device__ __forceinline__ float wave_sum(float x) {
    x = dpp_add<0x111>(x);  // row_shr:1
    x = dpp_add<0x112>(x);  // row_shr:2
    x = dpp_add<0x114>(x);  // row_shr:4
    x = dpp_add<0x118>(x);  // row_shr:8  -> lane15 of each 16-row has row sum
    x = dpp_add<0x142>(x);  // row_bcast:15 -> lane31=R0+R1, lane63=R2+R3
    x = dpp_add<0x143>(x);  // row_bcast:31 -> lane63 = total
    return __int_as_float(__builtin_amdgcn_readlane(__float_as_int(x), 63));
}

__global__ __launch_bounds__(256, 4) void pgd_kernel(
        const float* __restrict__ x,
        const int*   __restrict__ y,
        double*      __restrict__ acc) {
    const int wave = threadIdx.x >> 6;     // 0..3 (4 rows per block)
    const int lane = threadIdx.x & 63;
    const int row  = (blockIdx.x << 2) + wave;

    const float* __restrict__ xr = x + (size_t)row * NC;

    float c[EPJ];   // normalized logits (tau = 1)
    float p[EPJ];
    float v[EPJ];

    // ---- load row + sum of squares (L2 normalize, ref: x / max(||x||,1e-12)) ----
    float ss = 0.f;
#pragma unroll
    for (int j = 0; j < EPJ; ++j) {
        const int e = j * 64 + lane;
        float xv = (e < NC) ? xr[e] : 0.f;
        c[j] = xv;
        ss += xv * xv;
    }
    ss = wave_sum(ss);
    const float norm = fmaxf(sqrtf(ss), 1e-12f);
#pragma unroll
    for (int j = 0; j < EPJ; ++j) c[j] = c[j] / norm;

#pragma unroll
    for (int j = 0; j < EPJ; ++j) p[j] = KVAL / (float)NC;  // 0.005

    const bool valid15 = lane < (NC - 15 * 64);  // lane < 40 for j==15

    for (int it = 0; it < N_ITER; ++it) {
        // ---- ascent: v = p + alpha*(c + ln2*(log2(1-pc) - log2(pc))) ----
        // v in [0.30, 0.91] for all reachable p (|c|<=1), so upper clip of the
        // projection is never active and s(nu)=sum relu(v-nu) is CONVEX.
        float sv = 0.f;
#pragma unroll
        for (int j = 0; j < EPJ; ++j) {
            float pc = fminf(fmaxf(p[j], EPS_P), 1.f - EPS_P);
            float d  = __log2f(1.f - pc) - __log2f(pc);
            float g  = fmaf(LN2, d, c[j]);
            float vj = fmaf(ALPHA, g, p[j]);
            if (j == 15) vj = valid15 ? vj : 0.f;   // pads: relu(0-nu)=0 since nu>0
            v[j] = vj;
            sv += vj;
        }
        sv = wave_sum(sv);

        // ---- exact projection: Newton on convex piecewise-linear s(nu)=K ----
        // Start at all-interior estimate nu0 = (sum v - K)/n <= nu* (since
        // relu(t) >= t => s(nu0) >= K). Tangent of a convex function lies
        // below it, so every Newton iterate stays <= nu* and increases:
        // monotone, exact once in the root's segment. m>=1 whenever s>K.
        float nu = (sv - KVAL) * (1.0f / (float)NC);
        for (int pass = 0; pass < MAX_SOLVE; ++pass) {
            float s = 0.f;
            int   m = 0;
#pragma unroll
            for (int j = 0; j < EPJ; ++j) {
                float t = v[j] - nu;
                s += fmaxf(t, 0.f);
                m += (int)__builtin_popcountll(__ballot(t > 0.f));  // slope (scalar pipe)
            }
            s = wave_sum(s);
            if (m == 0) break;                       // cannot happen from below; guard
            float step = (s - KVAL) / (float)m;
            nu += step;
            if (fabsf(step) < 3e-8f) break;          // ~1 ULP of nu: converged
        }

#pragma unroll
        for (int j = 0; j < EPJ; ++j)
            p[j] = fminf(fmaxf(v[j] - nu, 0.f), 1.f);
    }

    // ---- pick p[y], loss = -log(p_y + 1e-8) ----
    const int yv = y[row];          // wave-uniform
    const int jy = yv >> 6;
    const int ly = yv & 63;
    float sel = 0.f;
#pragma unroll
    for (int j = 0; j < EPJ; ++j) sel = (j == jy) ? p[j] : sel;
    const float py   = __shfl(sel, ly, 64);
    const float loss = -logf(py + 1e-8f);

    __shared__ float partial[4];
    if (lane == 0) partial[wave] = loss;
    __syncthreads();
    if (threadIdx.x == 0) {
        double t = (double)partial[0] + (double)partial[1]
                 + (double)partial[2] + (double)partial[3];
        atomicAdd(acc, t);
    }
}

__global__ void finalize_kernel(const double* __restrict__ acc,
                                float* __restrict__ out) {
    out[0] = (float)(acc[0] / (double)N_ROWS);
}

extern "C" void kernel_launch(void* const* d_in, const int* in_sizes, int n_in,
                              void* d_out, int out_size, void* d_ws, size_t ws_size,
                              hipStream_t stream) {
    const float* x = (const float*)d_in[0];
    const int*   y = (const int*)d_in[1];
    double* acc = (double*)d_ws;

    (void)hipMemsetAsync(acc, 0, sizeof(double), stream);   // ws poisoned 0xAA each call
    pgd_kernel<<<N_ROWS / 4, 256, 0, stream>>>(x, y, acc);
    finalize_kernel<<<1, 1, 0, stream>>>(acc, (float*)d_out);
}

// Round 5
// 558.214 us; speedup vs baseline: 10.9079x; 1.3584x over previous
//
#include <hip/hip_runtime.h>
#include <math.h>

// Problem constants (from reference)
#define N_ROWS    16384
#define NC        1000
#define KVAL      5.0f
#define ALPHA     0.025f
#define N_ITER    80
#define MAX_SOLVE 12        // Newton passes; warm-started, early-exits in 1-3
#define EPS_P     1e-6f
#define EPJ       16        // elements per lane: 16*64 = 1024 >= 1000
#define ALN2      0.0173286795139986f   // ALPHA * ln(2)

// One wave (64 lanes) per row; lane holds elements e = j*64 + lane.
// Invariants (provable for all p in [0,1], |c|<=~0.15):
//   v = p + alpha*(c + log((1-pc)/pc)) in [0.11, 0.92]
//   => upper clip of the projection NEVER binds, and s(0) = sum(v) >= 110 > K
//   => root nu* > 0, s(nu) = sum relu(v - nu) is CONVEX piecewise-linear.
// Newton on a convex function converges globally (one step from anywhere lands
// at-or-left of the root, then increases monotonically) => warm-start is safe.

template <int CTRL>
__device__ __forceinline__ float dpp_add(float x) {
    int t = __builtin_amdgcn_update_dpp(0, __float_as_int(x), CTRL, 0xf, 0xf, true);
    return x + __int_as_float(t);
}

// Full 64-lane sum -> uniform via readlane(63).
__device__ __forceinline__ float wave_sum(float x) {
    x = dpp_add<0x111>(x);  // row_shr:1
    x = dpp_add<0x112>(x);  // row_shr:2
    x = dpp_add<0x114>(x);  // row_shr:4
    x = dpp_add<0x118>(x);  // row_shr:8
    x = dpp_add<0x142>(x);  // row_bcast:15
    x = dpp_add<0x143>(x);  // row_bcast:31 -> lane63 = total
    return __int_as_float(__builtin_amdgcn_readlane(__float_as_int(x), 63));
}

__global__ __launch_bounds__(256, 4) void pgd_kernel(
        const float* __restrict__ x,
        const int*   __restrict__ y,
        double*      __restrict__ acc) {
    const int wave = threadIdx.x >> 6;     // 0..3 (4 rows per block)
    const int lane = threadIdx.x & 63;
    const int row  = (blockIdx.x << 2) + wave;

    const float* __restrict__ xr = x + (size_t)row * NC;

    float cc[EPJ];  // ALPHA * normalized logits
    float p[EPJ];
    float v[EPJ];

    // ---- load row + sum of squares (L2 normalize, ref: x / max(||x||,1e-12)) ----
    float ss = 0.f;
#pragma unroll
    for (int j = 0; j < EPJ; ++j) {
        const int e = j * 64 + lane;
        float xv = (e < NC) ? xr[e] : 0.f;
        cc[j] = xv;
        ss += xv * xv;
    }
    ss = wave_sum(ss);
    const float sc = ALPHA / fmaxf(sqrtf(ss), 1e-12f);
#pragma unroll
    for (int j = 0; j < EPJ; ++j) cc[j] *= sc;

#pragma unroll
    for (int j = 0; j < EPJ; ++j) p[j] = KVAL / (float)NC;  // 0.005

    const bool valid15 = lane < (NC - 15 * 64);  // lane < 40 for j==15

    // Warm-start state: the dynamics settle onto a period-2 cycle, so nu from
    // TWO iterations back is phase-matched (often bitwise-equal -> 1 pass).
    float nu_m1 = 0.f, nu_m2 = 0.f;

    for (int it = 0; it < N_ITER; ++it) {
        // ---- ascent: v = (p + alpha*c) + alpha*ln2*(log2(1-pc) - log2(pc)) ----
        // p in [0, 0.92] => pc = max(p, EPS) suffices (upper clamp never binds).
#pragma unroll
        for (int j = 0; j < EPJ; ++j) {
            float pc = fmaxf(p[j], EPS_P);
            float d  = __log2f(1.f - pc) - __log2f(pc);
            float vj = fmaf(ALN2, d, p[j] + cc[j]);
            if (j == 15) vj = valid15 ? vj : 0.f;   // pads: relu(0-nu)=0 since nu>0
            v[j] = vj;
        }

        // ---- projection: Newton on convex s(nu)=K, warm-started, fused update ----
        float nu = nu_m2;           // phase-matched warm start (iter 0/1: 0 < nu*)
        for (int pass = 0; pass < MAX_SOLVE; ++pass) {
            float s = 0.f;
            int   m = 0;
#pragma unroll
            for (int j = 0; j < EPJ; ++j) {
                float t  = v[j] - nu;
                float tc = fmaxf(t, 0.f);
                p[j] = tc;                                           // fused update
                s += tc;
                m += (int)__builtin_popcountll(__ballot(t > 0.f));   // slope
            }
            s = wave_sum(s);
            if (m == 0) { nu = 0.f; continue; }      // restart below root (s(0)>K)
            float step = (s - KVAL) / (float)m;
            nu += step;
            if (fabsf(step) < 3e-8f) break;          // ~1 ULP: p already at nu_final
        }
        nu_m2 = nu_m1;
        nu_m1 = nu;
    }

    // ---- pick p[y], loss = -log(p_y + 1e-8) ----
    const int yv = y[row];          // wave-uniform
    const int jy = yv >> 6;
    const int ly = yv & 63;
    float sel = 0.f;
#pragma unroll
    for (int j = 0; j < EPJ; ++j) sel = (j == jy) ? p[j] : sel;
    const float py   = __shfl(sel, ly, 64);
    const float loss = -logf(py + 1e-8f);

    __shared__ float partial[4];
    if (lane == 0) partial[wave] = loss;
    __syncthreads();
    if (threadIdx.x == 0) {
        double t = (double)partial[0] + (double)partial[1]
                 + (double)partial[2] + (double)partial[3];
        atomicAdd(acc, t);
    }
}

__global__ void finalize_kernel(const double* __restrict__ acc,
                                float* __restrict__ out) {
    out[0] = (float)(acc[0] / (double)N_ROWS);
}

extern "C" void kernel_launch(void* const* d_in, const int* in_sizes, int n_in,
                              void* d_out, int out_size, void* d_ws, size_t ws_size,
                              hipStream_t stream) {
    const float* x = (const float*)d_in[0];
    const int*   y = (const int*)d_in[1];
    double* acc = (double*)d_ws;

    (void)hipMemsetAsync(acc, 0, sizeof(double), stream);   // ws poisoned 0xAA each call
    pgd_kernel<<<N_ROWS / 4, 256, 0, stream>>>(x, y, acc);
    finalize_kernel<<<1, 1, 0, stream>>>(acc, (float*)d_out);
}

// Round 6
// 223.949 us; speedup vs baseline: 27.1889x; 2.4926x over previous
//
#include <hip/hip_runtime.h>
#include <math.h>

// Problem constants (from reference)
#define N_ROWS    16384
#define NC        1000
#define KVAL      5.0f
#define ALPHA     0.025f
#define N_ITER    80
#define MAX_SOLVE 12        // Newton passes; warm-started, early-exits in 1-3
#define EPS_P     1e-6f
#define EPJ       16        // elements per lane: 16*64 = 1024 >= 1000
#define ALN2      0.0173286795139986f   // ALPHA * ln(2)

// One wave (64 lanes) per row; lane holds elements e = j*64 + lane.
// Invariants (provable for all p in [0,1], |c|<=~0.15):
//   v = p + alpha*(c + log((1-pc)/pc)) in [0.11, 0.92]
//   => upper clip never binds; s(0)=sum(v) >= 110 > K => nu* > 0;
//   s(nu) = sum relu(v-nu) is CONVEX piecewise-linear => Newton converges
//   globally & monotonically after one step from ANY start => warm-start safe.
// Dynamics: multiplier 1 - alpha/(p(1-p)) ~ -4 at p~0.005 => PGD oscillates
// onto a superstable flush cycle (every positive element clips to exactly 0
// each iter; membership sets alternate). Once flushed, state is a function of
// (c, membership) only => trajectory is BITWISE period-2. We detect that and
// exit early (checked at odd it => completed count even, matching N_ITER=80).

template <int CTRL>
__device__ __forceinline__ float dpp_add(float x) {
    int t = __builtin_amdgcn_update_dpp(0, __float_as_int(x), CTRL, 0xf, 0xf, true);
    return x + __int_as_float(t);
}

// Full 64-lane sum -> uniform via readlane(63).
__device__ __forceinline__ float wave_sum(float x) {
    x = dpp_add<0x111>(x);  // row_shr:1
    x = dpp_add<0x112>(x);  // row_shr:2
    x = dpp_add<0x114>(x);  // row_shr:4
    x = dpp_add<0x118>(x);  // row_shr:8
    x = dpp_add<0x142>(x);  // row_bcast:15
    x = dpp_add<0x143>(x);  // row_bcast:31 -> lane63 = total
    return __int_as_float(__builtin_amdgcn_readlane(__float_as_int(x), 63));
}

__global__ __launch_bounds__(256, 4) void pgd_kernel(
        const float* __restrict__ x,
        const int*   __restrict__ y,
        double*      __restrict__ acc) {
    const int wave = threadIdx.x >> 6;     // 0..3 (4 rows per block)
    const int lane = threadIdx.x & 63;
    const int row  = (blockIdx.x << 2) + wave;

    const float* __restrict__ xr = x + (size_t)row * NC;

    float cc[EPJ];  // ALPHA * normalized logits
    float p[EPJ];
    float v[EPJ];
    float pp[EPJ];  // p two iterations back (odd-completion snapshots)

    // ---- load row + sum of squares (L2 normalize, ref: x / max(||x||,1e-12)) ----
    float ss = 0.f;
#pragma unroll
    for (int j = 0; j < EPJ; ++j) {
        const int e = j * 64 + lane;
        float xv = (e < NC) ? xr[e] : 0.f;
        cc[j] = xv;
        ss += xv * xv;
    }
    ss = wave_sum(ss);
    const float sc = ALPHA / fmaxf(sqrtf(ss), 1e-12f);
#pragma unroll
    for (int j = 0; j < EPJ; ++j) cc[j] *= sc;

    const bool valid15 = lane < (NC - 15 * 64);  // lane < 40 for j==15

#pragma unroll
    for (int j = 0; j < EPJ; ++j) {
        p[j]  = KVAL / (float)NC;   // 0.005
        pp[j] = -1.f;               // impossible value: first compare fails
    }
    if (!valid15) pp[15] = 0.f;     // pad lanes: p[15] is always 0 -> compare true

    // Warm-start state: nu from two iterations back is phase-matched.
    float nu_m1 = 0.f, nu_m2 = 0.f;

    for (int it = 0; it < N_ITER; ++it) {
        // ---- ascent: v = (p + alpha*c) + alpha*ln2*(log2(1-pc) - log2(pc)) ----
#pragma unroll
        for (int j = 0; j < EPJ; ++j) {
            float pc = fmaxf(p[j], EPS_P);
            float d  = __log2f(1.f - pc) - __log2f(pc);
            float vj = fmaf(ALN2, d, p[j] + cc[j]);
            if (j == 15) vj = valid15 ? vj : 0.f;   // pads: relu(0-nu)=0 since nu>0
            v[j] = vj;
        }

        // ---- projection: Newton on convex s(nu)=K, warm-started, fused update ----
        float nu = nu_m2;
        for (int pass = 0; pass < MAX_SOLVE; ++pass) {
            float s = 0.f;
            int   m = 0;
#pragma unroll
            for (int j = 0; j < EPJ; ++j) {
                float t  = v[j] - nu;
                float tc = fmaxf(t, 0.f);
                p[j] = tc;                                           // fused update
                s += tc;
                m += (int)__builtin_popcountll(__ballot(t > 0.f));   // slope
            }
            s = wave_sum(s);
            if (m == 0) { nu = 0.f; continue; }      // restart below root (s(0)>K)
            float step = (s - KVAL) / (float)m;
            nu += step;
            if (fabsf(step) < 3e-8f) break;          // ~1 ULP: p already consistent
        }
        nu_m2 = nu_m1;
        nu_m1 = nu;

        // ---- period-2 detection at odd it (completed count even, like 80) ----
        if (it & 1) {
            unsigned long long eq = ~0ull;
#pragma unroll
            for (int j = 0; j < EPJ; ++j) {
                eq &= __ballot(p[j] == pp[j]);
                pp[j] = p[j];
            }
            if (eq == ~0ull) break;   // bitwise period-2: P_final == P_current
        }
    }

    // ---- pick p[y], loss = -log(p_y + 1e-8) ----
    const int yv = y[row];          // wave-uniform
    const int jy = yv >> 6;
    const int ly = yv & 63;
    float sel = 0.f;
#pragma unroll
    for (int j = 0; j < EPJ; ++j) sel = (j == jy) ? p[j] : sel;
    const float py   = __shfl(sel, ly, 64);
    const float loss = -logf(py + 1e-8f);

    __shared__ float partial[4];
    if (lane == 0) partial[wave] = loss;
    __syncthreads();
    if (threadIdx.x == 0) {
        double t = (double)partial[0] + (double)partial[1]
                 + (double)partial[2] + (double)partial[3];
        atomicAdd(acc, t);
    }
}

__global__ void finalize_kernel(const double* __restrict__ acc,
                                float* __restrict__ out) {
    out[0] = (float)(acc[0] / (double)N_ROWS);
}

extern "C" void kernel_launch(void* const* d_in, const int* in_sizes, int n_in,
                              void* d_out, int out_size, void* d_ws, size_t ws_size,
                              hipStream_t stream) {
    const float* x = (const float*)d_in[0];
    const int*   y = (const int*)d_in[1];
    double* acc = (double*)d_ws;

    (void)hipMemsetAsync(acc, 0, sizeof(double), stream);   // ws poisoned 0xAA each call
    pgd_kernel<<<N_ROWS / 4, 256, 0, stream>>>(x, y, acc);
    finalize_kernel<<<1, 1, 0, stream>>>(acc, (float*)d_out);
}